// Round 10
// baseline (351.154 us; speedup 1.0000x reference)
//
#include <hip/hip_runtime.h>

#define KC 4096
#define DD 256
#define BB 32768
#define P_BETA 0.25f
#define P_DECAY 0.99f
#define P_EPS 1e-5f
#define TAU 0.5f

typedef __attribute__((ext_vector_type(8))) short bf16x8;
typedef __attribute__((ext_vector_type(4))) float f32x4;

static __device__ __forceinline__ unsigned short f2bf(float f) {
    unsigned int u = __float_as_uint(f);
    unsigned int r = (u + 0x7fffu + ((u >> 16) & 1u)) >> 16;
    return (unsigned short)r;
}
static __device__ __forceinline__ void gload_lds16(const void* g, void* s) {
    __builtin_amdgcn_global_load_lds(
        (const __attribute__((address_space(1))) unsigned int*)g,
        (__attribute__((address_space(3))) unsigned int*)s, 16, 0, 0);
}

// ---------------------------------------------------------------------------
// Fused prep: blocks [0,8192) convert z; [8192,9216) convert cb + c_norm;
// block 9216 zeros cnt; blocks [9217, 9217+1024) pre-init
// out_emaw = ema_w * DECAY  (the atomic target for the fused EMA scatter).
// ---------------------------------------------------------------------------
#define ZBLK (BB * DD / 4 / 256)   // 8192
#define CBLK (KC * DD / 4 / 256)   // 1024
#define EBLK (KC * DD / 4 / 256)   // 1024
__global__ __launch_bounds__(256) void convert_all_kernel(
    const float* __restrict__ z, const float* __restrict__ cb,
    unsigned short* __restrict__ zb, unsigned short* __restrict__ cbb,
    float* __restrict__ cn, int* __restrict__ cnt,
    const float* __restrict__ ema_w, float* __restrict__ out_emaw) {
    const int b = blockIdx.x;
    if (b < ZBLK) {
        int t = b * 256 + threadIdx.x;
        float4 v = ((const float4*)z)[t];
        *(ushort4*)&zb[(size_t)t * 4] =
            make_ushort4(f2bf(v.x), f2bf(v.y), f2bf(v.z), f2bf(v.w));
    } else if (b < ZBLK + CBLK) {
        int t = (b - ZBLK) * 256 + threadIdx.x;
        int lane = threadIdx.x & 63;
        int row = (b - ZBLK) * 4 + (threadIdx.x >> 6);
        float4 v = ((const float4*)cb)[t];
        *(ushort4*)&cbb[(size_t)t * 4] =
            make_ushort4(f2bf(v.x), f2bf(v.y), f2bf(v.z), f2bf(v.w));
        float s = v.x * v.x + v.y * v.y + v.z * v.z + v.w * v.w;
#pragma unroll
        for (int m = 32; m; m >>= 1) s += __shfl_xor(s, m);
        if (lane == 0) cn[row] = s;
    } else if (b == ZBLK + CBLK) {
        // zero cnt: 4096 ints = 1024 int4, 4 per thread
        int4* p = (int4*)cnt;
        int4 zv = make_int4(0, 0, 0, 0);
#pragma unroll
        for (int j = 0; j < 4; ++j) p[threadIdx.x * 4 + j] = zv;
    } else {
        int t = (b - ZBLK - CBLK - 1) * 256 + threadIdx.x;
        float4 v = ((const float4*)ema_w)[t];
        ((float4*)out_emaw)[t] =
            make_float4(v.x * P_DECAY, v.y * P_DECAY, v.z * P_DECAY, v.w * P_DECAY);
    }
}

// ---------------------------------------------------------------------------
// MFMA argmin screening (plain bf16), persistent A-tile, XOR swizzle.
// EXACT R0 anchor schedule: 4 waves, 2-barrier dc loop, As 64 KB persistent
// + Bs 16 KB, 2 blocks/CU, VGPR 96 (no spill).  90.7 us measured.
// Emits per-row top-2 per K-half.
// ---------------------------------------------------------------------------
__global__ __launch_bounds__(256, 2) void
mfma_argmin_kernel(const unsigned short* __restrict__ zb,
                   const unsigned short* __restrict__ cbb,
                   const float* __restrict__ cn,
                   float4* __restrict__ cand) {
    __shared__ unsigned short As[128 * 256];  // 64 KB persistent z-tile
    __shared__ unsigned short Bs[128 * 64];   // 16 KB per-step cb-tile

    const int tid = threadIdx.x;
    const int l = tid & 63, w = tid >> 6;
    const int xcd = blockIdx.x & 7;
    const int half = xcd >> 2;
    const int rb = (blockIdx.x >> 3) * 4 + (xcd & 3);
    const int row0 = rb * 128;
    const int col0 = half * 2048;
    const int wm = w & 1, wn = w >> 1;
    const int m_off = wm * 64, n_off = wn * 64;
    const int lm = l & 15, lq = l >> 4;

    {
        const int lrow = w * 2 + (l >> 5);
        const int coff = ((l & 31) ^ lrow) * 8;
#pragma unroll
        for (int i = 0; i < 16; ++i) {
            gload_lds16(zb + (size_t)(row0 + i * 8 + lrow) * DD + coff,
                        &As[(i * 8 + w * 2) * 256]);
        }
    }

    const int srow = l >> 3;
    const int scol = ((l & 7) ^ srow) * 8;
    const int g0 = w * 4;

    float best[16];
    int bidx[16];
#pragma unroll
    for (int s = 0; s < 16; ++s) { best[s] = 3.4e38f; bidx[s] = 0; }

    for (int kc = 0; kc < 2048; kc += 128) {
        f32x4 acc[4][4];
#pragma unroll
        for (int a = 0; a < 4; ++a)
#pragma unroll
            for (int b = 0; b < 4; ++b) acc[a][b] = (f32x4){0.f, 0.f, 0.f, 0.f};

        for (int dc = 0; dc < 4; ++dc) {
#pragma unroll
            for (int j = 0; j < 4; ++j) {
                const int g = g0 + j;
                const int br = col0 + kc + g * 8 + srow;
                gload_lds16(cbb + (size_t)br * DD + dc * 64 + scol, &Bs[g * 512]);
            }
            __syncthreads();
#pragma unroll
            for (int ks = 0; ks < 2; ++ks) {
                bf16x8 af[4], bfr[4];
                const int cbi = dc * 8 + ks * 4 + lq;
#pragma unroll
                for (int tm = 0; tm < 4; ++tm) {
                    int r = m_off + tm * 16 + lm;
                    af[tm] = *(const bf16x8*)&As[r * 256 + ((cbi ^ (r & 7)) * 8)];
                }
#pragma unroll
                for (int tn = 0; tn < 4; ++tn) {
                    int r = n_off + tn * 16 + lm;
                    bfr[tn] = *(const bf16x8*)&Bs[r * 64 + (((ks * 4 + lq) ^ (r & 7)) * 8)];
                }
#pragma unroll
                for (int tm = 0; tm < 4; ++tm)
#pragma unroll
                    for (int tn = 0; tn < 4; ++tn)
                        acc[tm][tn] = __builtin_amdgcn_mfma_f32_16x16x32_bf16(
                            af[tm], bfr[tn], acc[tm][tn], 0, 0, 0);
            }
            __syncthreads();
        }
#pragma unroll
        for (int tn = 0; tn < 4; ++tn) {
            const int col = col0 + kc + n_off + tn * 16 + lm;
            const float cnv = cn[col];
#pragma unroll
            for (int tm = 0; tm < 4; ++tm)
#pragma unroll
                for (int r = 0; r < 4; ++r) {
                    float dist = fmaf(-2.0f, acc[tm][tn][r], cnv);
                    int s = tm * 4 + r;
                    if (dist < best[s]) { best[s] = dist; bidx[s] = col; }
                }
        }
    }

    float v2[16];
    int i2[16];
#pragma unroll
    for (int s = 0; s < 16; ++s) { v2[s] = 3.4e38f; i2[s] = 0x7fffffff; }
#pragma unroll
    for (int m = 1; m < 16; m <<= 1) {
#pragma unroll
        for (int s = 0; s < 16; ++s) {
            float w1 = __shfl_xor(best[s], m); int j1 = __shfl_xor(bidx[s], m);
            float w2 = __shfl_xor(v2[s], m);   int j2 = __shfl_xor(i2[s], m);
            bool b = (w1 < best[s]) || (w1 == best[s] && j1 < bidx[s]);
            if (b) {
                bool c = (best[s] < w2) || (best[s] == w2 && bidx[s] < j2);
                v2[s] = c ? best[s] : w2; i2[s] = c ? bidx[s] : j2;
                best[s] = w1; bidx[s] = j1;
            } else {
                bool c = (w1 < v2[s]) || (w1 == v2[s] && j1 < i2[s]);
                v2[s] = c ? w1 : v2[s]; i2[s] = c ? j1 : i2[s];
            }
        }
    }

    float4* red = (float4*)As;
    if (lm == 0) {
#pragma unroll
        for (int tm = 0; tm < 4; ++tm)
#pragma unroll
            for (int r = 0; r < 4; ++r) {
                int s = tm * 4 + r;
                int row_local = m_off + tm * 16 + lq * 4 + r;
                red[wn * 128 + row_local] =
                    make_float4(best[s], __int_as_float(bidx[s]), v2[s], __int_as_float(i2[s]));
            }
    }
    __syncthreads();
    if (tid < 128) {
        float4 a = red[tid], b = red[128 + tid];
        float av1 = a.x, av2 = a.z; int ai1 = __float_as_int(a.y), ai2 = __float_as_int(a.w);
        float bv1 = b.x, bv2 = b.z; int bi1 = __float_as_int(b.y), bi2 = __float_as_int(b.w);
        float v1o, v2o; int i1o, i2o;
        bool bb = (bv1 < av1) || (bv1 == av1 && bi1 < ai1);
        if (bb) {
            v1o = bv1; i1o = bi1;
            bool c = (av1 < bv2) || (av1 == bv2 && ai1 < bi2);
            v2o = c ? av1 : bv2; i2o = c ? ai1 : bi2;
        } else {
            v1o = av1; i1o = ai1;
            bool c = (bv1 < av2) || (bv1 == av2 && bi1 < ai2);
            v2o = c ? bv1 : av2; i2o = c ? bi1 : ai2;
        }
        cand[(size_t)half * BB + row0 + tid] =
            make_float4(v1o, __int_as_float(i1o), v2o, __int_as_float(i2o));
    }
}

// ---------------------------------------------------------------------------
// FUSED back half (R10): merge halves + exact f32 re-check + z_q gather +
// commit partials + cnt hist + DIRECT EMA atomic scatter into out_emaw.
// Wave-per-row: grid BB/4 = 8192 blocks x 4 waves.  One z read total
// (was up to 3 across merge/zq/bucket); cb[i1o] gather doubles as the zq
// output when kb==i1o.  Replaces 3 kernels + row_of/cursor machinery.
// ---------------------------------------------------------------------------
__global__ __launch_bounds__(256) void merge_zq_kernel(
    const float4* __restrict__ cand, const float* __restrict__ z,
    const float* __restrict__ cb, const float* __restrict__ cn,
    float* __restrict__ idx_f, int* __restrict__ cnt,
    float* __restrict__ zq, float* __restrict__ commit_parts,
    float* __restrict__ out_emaw) {
    const int w = threadIdx.x >> 6, l = threadIdx.x & 63;
    const int i = blockIdx.x * 4 + w;
    float4 a = cand[i], b = cand[(size_t)BB + i];
    float av1 = a.x, av2 = a.z; int ai1 = __float_as_int(a.y), ai2 = __float_as_int(a.w);
    float bv1 = b.x, bv2 = b.z; int bi1 = __float_as_int(b.y), bi2 = __float_as_int(b.w);
    float v1o, v2o; int i1o, i2o;
    bool bb = (bv1 < av1) || (bv1 == av1 && bi1 < ai1);
    if (bb) {
        v1o = bv1; i1o = bi1;
        bool c = (av1 < bv2) || (av1 == bv2 && ai1 < bi2);
        v2o = c ? av1 : bv2; i2o = c ? ai1 : bi2;
    } else {
        v1o = av1; i1o = ai1;
        bool c = (bv1 < av2) || (bv1 == av2 && bi1 < ai2);
        v2o = c ? bv1 : av2; i2o = c ? bi1 : ai2;
    }
    float4 zv = ((const float4*)z)[(size_t)i * 64 + l];
    float4 p = ((const float4*)cb)[(size_t)i1o * 64 + l];
    int kb = i1o;
    float4 cv = p;
    if (v2o - v1o < TAU) {          // wave-uniform branch
        float4 q = ((const float4*)cb)[(size_t)i2o * 64 + l];
        float s1 = zv.x * p.x + zv.y * p.y + zv.z * p.z + zv.w * p.w;
        float s2 = zv.x * q.x + zv.y * q.y + zv.z * q.z + zv.w * q.w;
#pragma unroll
        for (int m = 32; m; m >>= 1) {
            s1 += __shfl_xor(s1, m);
            s2 += __shfl_xor(s2, m);
        }
        float d1 = cn[i1o] - 2.f * s1;
        float d2 = cn[i2o] - 2.f * s2;
        if (d2 < d1 || (d2 == d1 && i2o < i1o)) { kb = i2o; cv = q; }
    }
    ((float4*)zq)[(size_t)i * 64 + l] = cv;
    float dx = zv.x - cv.x, dy = zv.y - cv.y, dz = zv.z - cv.z, dq = zv.w - cv.w;
    float s = dx * dx + dy * dy + dz * dz + dq * dq;
#pragma unroll
    for (int m = 32; m; m >>= 1) s += __shfl_xor(s, m);
    // direct EMA scatter: out_emaw pre-inited to ema_w*DECAY in convert
    const float sc = 1.0f - P_DECAY;
    float* dst = out_emaw + (size_t)kb * DD + l * 4;
    atomicAdd(dst + 0, zv.x * sc);
    atomicAdd(dst + 1, zv.y * sc);
    atomicAdd(dst + 2, zv.z * sc);
    atomicAdd(dst + 3, zv.w * sc);
    __shared__ float ls[4];
    if (l == 0) {
        ls[w] = s;
        idx_f[i] = (float)kb;
        atomicAdd(&cnt[kb], 1);
    }
    __syncthreads();
    if (threadIdx.x == 0) commit_parts[blockIdx.x] = ls[0] + ls[1] + ls[2] + ls[3];
}

// ---------------------------------------------------------------------------
// FUSED finalize (R10): blocks 0..1023 each redundantly compute
// n = sum(new_cluster) from cnt+ema_cs (32 KB, L2-hot, same summation order
// as the old prefix kernel -> deterministic), write out_cluster for their
// own 4 rows, and emit out_codebook = out_emaw / csz.
// Block 1024: commit reduce.   Replaces prefix + codebook launches.
// ---------------------------------------------------------------------------
__global__ __launch_bounds__(256) void finalize_kernel(
    const int* __restrict__ cnt, const float* __restrict__ ema_cs,
    const float* __restrict__ out_emaw, const float* __restrict__ commit_parts,
    float* __restrict__ out_cluster, float* __restrict__ out_codebook,
    float* __restrict__ out_commit) {
    const int t = threadIdx.x;
    if (blockIdx.x == KC / 4) {
        float cs = 0.f;
        for (int j = t; j < BB / 4; j += 256) cs += commit_parts[j];
#pragma unroll
        for (int m = 32; m; m >>= 1) cs += __shfl_xor(cs, m);
        __shared__ float lc[4];
        if ((t & 63) == 0) lc[t >> 6] = cs;
        __syncthreads();
        if (t == 0)
            *out_commit = P_BETA * (lc[0] + lc[1] + lc[2] + lc[3]) / (float)((size_t)BB * DD);
        return;
    }
    // redundant n (same order as old prefix kernel)
    float ns = 0.f;
#pragma unroll
    for (int j = 0; j < 16; ++j) {
        int kk = t * 16 + j;
        float nc = ema_cs[kk] * P_DECAY + (float)cnt[kk] * (1.0f - P_DECAY);
        ns += nc;
    }
#pragma unroll
    for (int m = 32; m; m >>= 1) ns += __shfl_xor(ns, m);
    __shared__ float lns[4];
    if ((t & 63) == 0) lns[t >> 6] = ns;
    __syncthreads();
    const float n = lns[0] + lns[1] + lns[2] + lns[3];

    const int id4 = blockIdx.x * 256 + t;   // float4 index
    const int k = id4 >> 6;                 // 64 float4 per row
    float cl = ema_cs[k] * P_DECAY + (float)cnt[k] * (1.0f - P_DECAY);
    if ((t & 63) == 0) out_cluster[k] = cl;
    float inv = 1.0f / ((cl + P_EPS) / (n + (float)KC * P_EPS) * n);
    float4 v = ((const float4*)out_emaw)[id4];
    ((float4*)out_codebook)[id4] =
        make_float4(v.x * inv, v.y * inv, v.z * inv, v.w * inv);
}

// ---------------------------------------------------------------------------
extern "C" void kernel_launch(void* const* d_in, const int* in_sizes, int n_in,
                              void* d_out, int out_size, void* d_ws, size_t ws_size,
                              hipStream_t stream) {
    const float* z      = (const float*)d_in[0];
    const float* cb     = (const float*)d_in[1];
    const float* ema_cs = (const float*)d_in[2];
    const float* ema_w  = (const float*)d_in[3];

    // workspace layout (16B-aligned first, then 4B scalars)
    float4* cand = (float4*)d_ws;                               // 2*BB float4
    unsigned short* zb = (unsigned short*)(cand + 2 * (size_t)BB);  // BB*DD bf16
    unsigned short* cbb = zb + (size_t)BB * DD;                 // KC*DD bf16
    float* c_norm = (float*)(cbb + (size_t)KC * DD);            // KC
    int* cnt = (int*)(c_norm + KC);                             // KC
    float* commit_parts = (float*)(cnt + KC);                   // BB/4

    float* out        = (float*)d_out;
    float* o_zq       = out;
    float* o_idx      = o_zq + (size_t)BB * DD;
    float* o_commit   = o_idx + BB;
    float* o_codebook = o_commit + 1;
    float* o_cluster  = o_codebook + (size_t)KC * DD;
    float* o_emaw     = o_cluster + KC;

    convert_all_kernel<<<ZBLK + CBLK + 1 + EBLK, 256, 0, stream>>>(
        z, cb, zb, cbb, c_norm, cnt, ema_w, o_emaw);
    mfma_argmin_kernel<<<(BB / 128) * 2, 256, 0, stream>>>(zb, cbb, c_norm, cand);
    merge_zq_kernel<<<BB / 4, 256, 0, stream>>>(cand, z, cb, c_norm, o_idx, cnt,
                                                o_zq, commit_parts, o_emaw);
    finalize_kernel<<<KC / 4 + 1, 256, 0, stream>>>(cnt, ema_cs, o_emaw,
                                                    commit_parts, o_cluster,
                                                    o_codebook, o_commit);
    (void)in_sizes; (void)n_in; (void)out_size; (void)ws_size;
}

// Round 11
// 225.989 us; speedup vs baseline: 1.5539x; 1.5539x over previous
//
#include <hip/hip_runtime.h>

#define KC 4096
#define DD 256
#define BB 32768
#define P_BETA 0.25f
#define P_DECAY 0.99f
#define P_EPS 1e-5f
#define TAU 0.5f
#define CHUNK 16

typedef __attribute__((ext_vector_type(8))) short bf16x8;
typedef __attribute__((ext_vector_type(4))) float f32x4;

static __device__ __forceinline__ unsigned short f2bf(float f) {
    unsigned int u = __float_as_uint(f);
    unsigned int r = (u + 0x7fffu + ((u >> 16) & 1u)) >> 16;
    return (unsigned short)r;
}
static __device__ __forceinline__ void gload_lds16(const void* g, void* s) {
    __builtin_amdgcn_global_load_lds(
        (const __attribute__((address_space(1))) unsigned int*)g,
        (__attribute__((address_space(3))) unsigned int*)s, 16, 0, 0);
}

// ---------------------------------------------------------------------------
// Fused prep: blocks [0,8192) convert z; [8192,9216) convert cb + c_norm;
// block 9216 zeros cnt; blocks [9217, 9217+1024) pre-init
// out_emaw = ema_w * DECAY  (the atomic target for bucket_scatter).
// ---------------------------------------------------------------------------
#define ZBLK (BB * DD / 4 / 256)   // 8192
#define CBLK (KC * DD / 4 / 256)   // 1024
#define EBLK (KC * DD / 4 / 256)   // 1024
__global__ __launch_bounds__(256) void convert_all_kernel(
    const float* __restrict__ z, const float* __restrict__ cb,
    unsigned short* __restrict__ zb, unsigned short* __restrict__ cbb,
    float* __restrict__ cn, int* __restrict__ cnt,
    const float* __restrict__ ema_w, float* __restrict__ out_emaw) {
    const int b = blockIdx.x;
    if (b < ZBLK) {
        int t = b * 256 + threadIdx.x;
        float4 v = ((const float4*)z)[t];
        *(ushort4*)&zb[(size_t)t * 4] =
            make_ushort4(f2bf(v.x), f2bf(v.y), f2bf(v.z), f2bf(v.w));
    } else if (b < ZBLK + CBLK) {
        int t = (b - ZBLK) * 256 + threadIdx.x;
        int lane = threadIdx.x & 63;
        int row = (b - ZBLK) * 4 + (threadIdx.x >> 6);
        float4 v = ((const float4*)cb)[t];
        *(ushort4*)&cbb[(size_t)t * 4] =
            make_ushort4(f2bf(v.x), f2bf(v.y), f2bf(v.z), f2bf(v.w));
        float s = v.x * v.x + v.y * v.y + v.z * v.z + v.w * v.w;
#pragma unroll
        for (int m = 32; m; m >>= 1) s += __shfl_xor(s, m);
        if (lane == 0) cn[row] = s;
    } else if (b == ZBLK + CBLK) {
        // zero cnt: 4096 ints = 1024 int4, 4 per thread
        int4* p = (int4*)cnt;
        int4 zv = make_int4(0, 0, 0, 0);
#pragma unroll
        for (int j = 0; j < 4; ++j) p[threadIdx.x * 4 + j] = zv;
    } else {
        int t = (b - ZBLK - CBLK - 1) * 256 + threadIdx.x;
        float4 v = ((const float4*)ema_w)[t];
        ((float4*)out_emaw)[t] =
            make_float4(v.x * P_DECAY, v.y * P_DECAY, v.z * P_DECAY, v.w * P_DECAY);
    }
}

// ---------------------------------------------------------------------------
// MFMA argmin screening (plain bf16), persistent A-tile, XOR swizzle.
// EXACT R0 anchor schedule: 4 waves, 2-barrier dc loop, As 64 KB persistent
// + Bs 16 KB, 2 blocks/CU, VGPR 96 (no spill).  90.7 us measured.
// Emits per-row top-2 per K-half.
// ---------------------------------------------------------------------------
__global__ __launch_bounds__(256, 2) void
mfma_argmin_kernel(const unsigned short* __restrict__ zb,
                   const unsigned short* __restrict__ cbb,
                   const float* __restrict__ cn,
                   float4* __restrict__ cand) {
    __shared__ unsigned short As[128 * 256];  // 64 KB persistent z-tile
    __shared__ unsigned short Bs[128 * 64];   // 16 KB per-step cb-tile

    const int tid = threadIdx.x;
    const int l = tid & 63, w = tid >> 6;
    const int xcd = blockIdx.x & 7;
    const int half = xcd >> 2;
    const int rb = (blockIdx.x >> 3) * 4 + (xcd & 3);
    const int row0 = rb * 128;
    const int col0 = half * 2048;
    const int wm = w & 1, wn = w >> 1;
    const int m_off = wm * 64, n_off = wn * 64;
    const int lm = l & 15, lq = l >> 4;

    {
        const int lrow = w * 2 + (l >> 5);
        const int coff = ((l & 31) ^ lrow) * 8;
#pragma unroll
        for (int i = 0; i < 16; ++i) {
            gload_lds16(zb + (size_t)(row0 + i * 8 + lrow) * DD + coff,
                        &As[(i * 8 + w * 2) * 256]);
        }
    }

    const int srow = l >> 3;
    const int scol = ((l & 7) ^ srow) * 8;
    const int g0 = w * 4;

    float best[16];
    int bidx[16];
#pragma unroll
    for (int s = 0; s < 16; ++s) { best[s] = 3.4e38f; bidx[s] = 0; }

    for (int kc = 0; kc < 2048; kc += 128) {
        f32x4 acc[4][4];
#pragma unroll
        for (int a = 0; a < 4; ++a)
#pragma unroll
            for (int b = 0; b < 4; ++b) acc[a][b] = (f32x4){0.f, 0.f, 0.f, 0.f};

        for (int dc = 0; dc < 4; ++dc) {
#pragma unroll
            for (int j = 0; j < 4; ++j) {
                const int g = g0 + j;
                const int br = col0 + kc + g * 8 + srow;
                gload_lds16(cbb + (size_t)br * DD + dc * 64 + scol, &Bs[g * 512]);
            }
            __syncthreads();
#pragma unroll
            for (int ks = 0; ks < 2; ++ks) {
                bf16x8 af[4], bfr[4];
                const int cbi = dc * 8 + ks * 4 + lq;
#pragma unroll
                for (int tm = 0; tm < 4; ++tm) {
                    int r = m_off + tm * 16 + lm;
                    af[tm] = *(const bf16x8*)&As[r * 256 + ((cbi ^ (r & 7)) * 8)];
                }
#pragma unroll
                for (int tn = 0; tn < 4; ++tn) {
                    int r = n_off + tn * 16 + lm;
                    bfr[tn] = *(const bf16x8*)&Bs[r * 64 + (((ks * 4 + lq) ^ (r & 7)) * 8)];
                }
#pragma unroll
                for (int tm = 0; tm < 4; ++tm)
#pragma unroll
                    for (int tn = 0; tn < 4; ++tn)
                        acc[tm][tn] = __builtin_amdgcn_mfma_f32_16x16x32_bf16(
                            af[tm], bfr[tn], acc[tm][tn], 0, 0, 0);
            }
            __syncthreads();
        }
#pragma unroll
        for (int tn = 0; tn < 4; ++tn) {
            const int col = col0 + kc + n_off + tn * 16 + lm;
            const float cnv = cn[col];
#pragma unroll
            for (int tm = 0; tm < 4; ++tm)
#pragma unroll
                for (int r = 0; r < 4; ++r) {
                    float dist = fmaf(-2.0f, acc[tm][tn][r], cnv);
                    int s = tm * 4 + r;
                    if (dist < best[s]) { best[s] = dist; bidx[s] = col; }
                }
        }
    }

    float v2[16];
    int i2[16];
#pragma unroll
    for (int s = 0; s < 16; ++s) { v2[s] = 3.4e38f; i2[s] = 0x7fffffff; }
#pragma unroll
    for (int m = 1; m < 16; m <<= 1) {
#pragma unroll
        for (int s = 0; s < 16; ++s) {
            float w1 = __shfl_xor(best[s], m); int j1 = __shfl_xor(bidx[s], m);
            float w2 = __shfl_xor(v2[s], m);   int j2 = __shfl_xor(i2[s], m);
            bool b = (w1 < best[s]) || (w1 == best[s] && j1 < bidx[s]);
            if (b) {
                bool c = (best[s] < w2) || (best[s] == w2 && bidx[s] < j2);
                v2[s] = c ? best[s] : w2; i2[s] = c ? bidx[s] : j2;
                best[s] = w1; bidx[s] = j1;
            } else {
                bool c = (w1 < v2[s]) || (w1 == v2[s] && j1 < i2[s]);
                v2[s] = c ? w1 : v2[s]; i2[s] = c ? j1 : i2[s];
            }
        }
    }

    float4* red = (float4*)As;
    if (lm == 0) {
#pragma unroll
        for (int tm = 0; tm < 4; ++tm)
#pragma unroll
            for (int r = 0; r < 4; ++r) {
                int s = tm * 4 + r;
                int row_local = m_off + tm * 16 + lq * 4 + r;
                red[wn * 128 + row_local] =
                    make_float4(best[s], __int_as_float(bidx[s]), v2[s], __int_as_float(i2[s]));
            }
    }
    __syncthreads();
    if (tid < 128) {
        float4 a = red[tid], b = red[128 + tid];
        float av1 = a.x, av2 = a.z; int ai1 = __float_as_int(a.y), ai2 = __float_as_int(a.w);
        float bv1 = b.x, bv2 = b.z; int bi1 = __float_as_int(b.y), bi2 = __float_as_int(b.w);
        float v1o, v2o; int i1o, i2o;
        bool bb = (bv1 < av1) || (bv1 == av1 && bi1 < ai1);
        if (bb) {
            v1o = bv1; i1o = bi1;
            bool c = (av1 < bv2) || (av1 == bv2 && ai1 < bi2);
            v2o = c ? av1 : bv2; i2o = c ? ai1 : bi2;
        } else {
            v1o = av1; i1o = ai1;
            bool c = (bv1 < av2) || (bv1 == av2 && bi1 < ai2);
            v2o = c ? bv1 : av2; i2o = c ? bi1 : ai2;
        }
        cand[(size_t)half * BB + row0 + tid] =
            make_float4(v1o, __int_as_float(i1o), v2o, __int_as_float(i2o));
    }
}

// ---------------------------------------------------------------------------
// FUSED (R11): merge halves + exact f32 re-check + z_q write + commit
// partials + idx + cnt hist.  Wave-per-row, grid BB/4 = 8192 blocks.
// z read ONCE; cb[i1o] gather doubles as zq output.  NO EMA atomics here
// (R10's 166 MB cross-XCD ping-pong) -- EMA goes via row_of bucket path.
// ---------------------------------------------------------------------------
__global__ __launch_bounds__(256) void merge_zq_kernel(
    const float4* __restrict__ cand, const float* __restrict__ z,
    const float* __restrict__ cb, const float* __restrict__ cn,
    int* __restrict__ idx_i, float* __restrict__ idx_f,
    int* __restrict__ cnt, float* __restrict__ zq,
    float* __restrict__ commit_parts) {
    const int w = threadIdx.x >> 6, l = threadIdx.x & 63;
    const int i = blockIdx.x * 4 + w;
    float4 a = cand[i], b = cand[(size_t)BB + i];
    float av1 = a.x, av2 = a.z; int ai1 = __float_as_int(a.y), ai2 = __float_as_int(a.w);
    float bv1 = b.x, bv2 = b.z; int bi1 = __float_as_int(b.y), bi2 = __float_as_int(b.w);
    float v1o, v2o; int i1o, i2o;
    bool bb = (bv1 < av1) || (bv1 == av1 && bi1 < ai1);
    if (bb) {
        v1o = bv1; i1o = bi1;
        bool c = (av1 < bv2) || (av1 == bv2 && ai1 < bi2);
        v2o = c ? av1 : bv2; i2o = c ? ai1 : bi2;
    } else {
        v1o = av1; i1o = ai1;
        bool c = (bv1 < av2) || (bv1 == av2 && bi1 < ai2);
        v2o = c ? bv1 : av2; i2o = c ? bi1 : ai2;
    }
    float4 zv = ((const float4*)z)[(size_t)i * 64 + l];
    float4 p = ((const float4*)cb)[(size_t)i1o * 64 + l];
    int kb = i1o;
    float4 cv = p;
    if (v2o - v1o < TAU) {          // wave-uniform branch
        float4 q = ((const float4*)cb)[(size_t)i2o * 64 + l];
        float s1 = zv.x * p.x + zv.y * p.y + zv.z * p.z + zv.w * p.w;
        float s2 = zv.x * q.x + zv.y * q.y + zv.z * q.z + zv.w * q.w;
#pragma unroll
        for (int m = 32; m; m >>= 1) {
            s1 += __shfl_xor(s1, m);
            s2 += __shfl_xor(s2, m);
        }
        float d1 = cn[i1o] - 2.f * s1;
        float d2 = cn[i2o] - 2.f * s2;
        if (d2 < d1 || (d2 == d1 && i2o < i1o)) { kb = i2o; cv = q; }
    }
    ((float4*)zq)[(size_t)i * 64 + l] = cv;
    float dx = zv.x - cv.x, dy = zv.y - cv.y, dz = zv.z - cv.z, dq = zv.w - cv.w;
    float s = dx * dx + dy * dy + dz * dz + dq * dq;
#pragma unroll
    for (int m = 32; m; m >>= 1) s += __shfl_xor(s, m);
    __shared__ float ls[4];
    if (l == 0) {
        ls[w] = s;
        idx_i[i] = kb;
        idx_f[i] = (float)kb;
        atomicAdd(&cnt[kb], 1);
    }
    __syncthreads();
    if (threadIdx.x == 0) commit_parts[blockIdx.x] = ls[0] + ls[1] + ls[2] + ls[3];
}

// ---------------------------------------------------------------------------
// Fused: exclusive prefix over 4096 bins -> cursor, PLUS new_cluster and
// n = sum(new_cluster).   1 block, 256 threads.
// ---------------------------------------------------------------------------
__global__ __launch_bounds__(256) void prefix_kernel(
    const int* __restrict__ cnt, int* __restrict__ cursor,
    const float* __restrict__ ema_cs, float* __restrict__ out_cluster,
    float* __restrict__ n_ws) {
    __shared__ int ls[257];
    __shared__ float lns[4];
    const int t = threadIdx.x;
    int local[16];
    int s = 0;
    float ns = 0.f;
#pragma unroll
    for (int j = 0; j < 16; ++j) {
        int c = cnt[t * 16 + j];
        local[j] = s; s += c;
        float nc = ema_cs[t * 16 + j] * P_DECAY + (float)c * (1.0f - P_DECAY);
        out_cluster[t * 16 + j] = nc;
        ns += nc;
    }
    ls[t + 1] = s;
#pragma unroll
    for (int m = 32; m; m >>= 1) ns += __shfl_xor(ns, m);
    if ((t & 63) == 0) lns[t >> 6] = ns;
    __syncthreads();
    if (t == 0) {
        ls[0] = 0;
        for (int j = 1; j <= 256; ++j) ls[j] += ls[j - 1];
        *n_ws = lns[0] + lns[1] + lns[2] + lns[3];
    }
    __syncthreads();
    int off = ls[t];
#pragma unroll
    for (int j = 0; j < 16; ++j) cursor[t * 16 + j] = off + local[j];
}

// ---------------------------------------------------------------------------
// Tiny bucket-id scatter: 128 blocks x 256 thr, one int atomic per row.
// (split out of the old zq kernel; builds the sorted row_of for the
// run-length-compressed EMA scatter)
// ---------------------------------------------------------------------------
__global__ __launch_bounds__(256) void scatter_kernel(
    const int* __restrict__ idx_i, int* __restrict__ cursor,
    int* __restrict__ row_of) {
    const int i = blockIdx.x * 256 + threadIdx.x;
    const int k = idx_i[i];
    int pos = atomicAdd(&cursor[k], 1);
    row_of[pos] = i | (k << 16);
}

// ---------------------------------------------------------------------------
// Balanced bucket scatter (position-space chunks, handles bucket skew):
// blocks 0..2047 process 16-row chunks of row_of, run-length-compress
// equal-k runs, atomicAdd acc*(1-DECAY) into out_emaw (pre-inited to
// ema_w*DECAY).   Block 2048: commit reduce.
// ---------------------------------------------------------------------------
__global__ __launch_bounds__(256) void bucket_scatter_kernel(
    const float* __restrict__ z, const int* __restrict__ row_of,
    float* __restrict__ out_emaw, const float* __restrict__ commit_parts,
    float* __restrict__ out_commit) {
    const int t = threadIdx.x;
    if (blockIdx.x == BB / CHUNK) {
        float cs = 0.f;
        for (int j = t; j < BB / 4; j += 256) cs += commit_parts[j];
#pragma unroll
        for (int m = 32; m; m >>= 1) cs += __shfl_xor(cs, m);
        __shared__ float lc[4];
        if ((t & 63) == 0) lc[t >> 6] = cs;
        __syncthreads();
        if (t == 0)
            *out_commit = P_BETA * (lc[0] + lc[1] + lc[2] + lc[3]) / (float)((size_t)BB * DD);
        return;
    }
    __shared__ int pk[CHUNK];
    const int p0 = blockIdx.x * CHUNK;
    if (t < CHUNK) pk[t] = row_of[p0 + t];
    __syncthreads();
    float acc = 0.f;
    int kprev = pk[0] >> 16;
#pragma unroll 4
    for (int j = 0; j < CHUNK; ++j) {
        int p = pk[j];
        int r = p & 0xffff, k = p >> 16;
        if (k != kprev) {
            atomicAdd(&out_emaw[(size_t)kprev * DD + t], acc * (1.0f - P_DECAY));
            acc = 0.f;
            kprev = k;
        }
        acc += z[(size_t)r * DD + t];
    }
    atomicAdd(&out_emaw[(size_t)kprev * DD + t], acc * (1.0f - P_DECAY));
}

// ---------------------------------------------------------------------------
// codebook = out_emaw / csz   (out_emaw is complete after bucket_scatter)
// 1024 blocks x 256 thr x float4.
// ---------------------------------------------------------------------------
__global__ __launch_bounds__(256) void codebook_kernel(
    const float* __restrict__ out_emaw, const float* __restrict__ out_cluster,
    const float* __restrict__ n_ws, float* __restrict__ out_codebook) {
    const int id4 = blockIdx.x * 256 + threadIdx.x;   // float4 index
    const int k = id4 >> 6;                            // 64 float4 per row
    const float n = *n_ws;
    float4 v = ((const float4*)out_emaw)[id4];
    float cl = out_cluster[k];
    float inv = 1.0f / ((cl + P_EPS) / (n + (float)KC * P_EPS) * n);
    ((float4*)out_codebook)[id4] =
        make_float4(v.x * inv, v.y * inv, v.z * inv, v.w * inv);
}

// ---------------------------------------------------------------------------
extern "C" void kernel_launch(void* const* d_in, const int* in_sizes, int n_in,
                              void* d_out, int out_size, void* d_ws, size_t ws_size,
                              hipStream_t stream) {
    const float* z      = (const float*)d_in[0];
    const float* cb     = (const float*)d_in[1];
    const float* ema_cs = (const float*)d_in[2];
    const float* ema_w  = (const float*)d_in[3];

    // workspace layout (16B-aligned first, then 4B scalars)
    float4* cand = (float4*)d_ws;                               // 2*BB float4
    unsigned short* zb = (unsigned short*)(cand + 2 * (size_t)BB);  // BB*DD bf16
    unsigned short* cbb = zb + (size_t)BB * DD;                 // KC*DD bf16
    float* c_norm = (float*)(cbb + (size_t)KC * DD);            // KC
    int* idx_i = (int*)(c_norm + KC);                           // BB
    int* cnt = idx_i + BB;                                      // KC
    int* cursor = cnt + KC;                                     // KC
    int* row_of = cursor + KC;                                  // BB
    float* commit_parts = (float*)(row_of + BB);                // BB/4
    float* n_ws = commit_parts + BB / 4;                        // 1

    float* out        = (float*)d_out;
    float* o_zq       = out;
    float* o_idx      = o_zq + (size_t)BB * DD;
    float* o_commit   = o_idx + BB;
    float* o_codebook = o_commit + 1;
    float* o_cluster  = o_codebook + (size_t)KC * DD;
    float* o_emaw     = o_cluster + KC;

    convert_all_kernel<<<ZBLK + CBLK + 1 + EBLK, 256, 0, stream>>>(
        z, cb, zb, cbb, c_norm, cnt, ema_w, o_emaw);
    mfma_argmin_kernel<<<(BB / 128) * 2, 256, 0, stream>>>(zb, cbb, c_norm, cand);
    merge_zq_kernel<<<BB / 4, 256, 0, stream>>>(cand, z, cb, c_norm, idx_i,
                                                o_idx, cnt, o_zq, commit_parts);
    prefix_kernel<<<1, 256, 0, stream>>>(cnt, cursor, ema_cs, o_cluster, n_ws);
    scatter_kernel<<<BB / 256, 256, 0, stream>>>(idx_i, cursor, row_of);
    bucket_scatter_kernel<<<BB / CHUNK + 1, 256, 0, stream>>>(
        z, row_of, o_emaw, commit_parts, o_commit);
    codebook_kernel<<<(KC * DD / 4) / 256, 256, 0, stream>>>(
        o_emaw, o_cluster, n_ws, o_codebook);
    (void)in_sizes; (void)n_in; (void)out_size; (void)ws_size;
}